// Round 9
// baseline (326.342 us; speedup 1.0000x reference)
//
#include <hip/hip_runtime.h>
#include <stdint.h>

typedef int v4i  __attribute__((ext_vector_type(4)));
typedef int v16i __attribute__((ext_vector_type(16)));

// ---------------------------------------------------------------------------
// Kernel 1: quantize activations fp32 -> int8, plus per-row sums.
// ---------------------------------------------------------------------------
__global__ void quant_x_kernel(const float* __restrict__ x,
                               int8_t* __restrict__ xq,
                               int* __restrict__ sum_x,
                               const float* __restrict__ p_scale,
                               const int* __restrict__ p_zp,
                               int K) {
    const int row = blockIdx.x;
    const int t = threadIdx.x;
    const float s = p_scale[0];
    const float zpf = (float)p_zp[0];
    const float* xr = x + (size_t)row * K;
    int8_t* qr = xq + (size_t)row * K;
    int lsum = 0;
    const int nchunk = K >> 10;
    for (int i = 0; i < nchunk; ++i) {
        const int idx = (i << 10) + (t << 2);
        const float4 v = *reinterpret_cast<const float4*>(xr + idx);
        const float f0 = fminf(fmaxf(rintf(v.x / s) + zpf, -128.f), 127.f);
        const float f1 = fminf(fmaxf(rintf(v.y / s) + zpf, -128.f), 127.f);
        const float f2 = fminf(fmaxf(rintf(v.z / s) + zpf, -128.f), 127.f);
        const float f3 = fminf(fmaxf(rintf(v.w / s) + zpf, -128.f), 127.f);
        const int i0 = (int)f0, i1 = (int)f1, i2 = (int)f2, i3 = (int)f3;
        lsum += i0 + i1 + i2 + i3;
        const unsigned pk = (unsigned)(i0 & 255) | ((unsigned)(i1 & 255) << 8) |
                            ((unsigned)(i2 & 255) << 16) | ((unsigned)(i3 & 255) << 24);
        *reinterpret_cast<unsigned*>(qr + idx) = pk;
    }
    __shared__ int wsum[4];
    #pragma unroll
    for (int off = 32; off > 0; off >>= 1) lsum += __shfl_down(lsum, off);
    if ((t & 63) == 0) wsum[t >> 6] = lsum;
    __syncthreads();
    if (t == 0) sum_x[row] = wsum[0] + wsum[1] + wsum[2] + wsum[3];
}

// ---------------------------------------------------------------------------
// Kernel 2: pack weight int32 (int8-valued) -> int8, plus per-row sums.
// ---------------------------------------------------------------------------
__global__ void quant_w_kernel(const int* __restrict__ w,
                               int8_t* __restrict__ wq,
                               int* __restrict__ sum_w,
                               int K) {
    const int row = blockIdx.x;
    const int t = threadIdx.x;
    const int* wr_ = w + (size_t)row * K;
    int8_t* qr = wq + (size_t)row * K;
    int lsum = 0;
    const int nchunk = K >> 10;
    for (int i = 0; i < nchunk; ++i) {
        const int idx = (i << 10) + (t << 2);
        const int4 v = *reinterpret_cast<const int4*>(wr_ + idx);
        lsum += v.x + v.y + v.z + v.w;
        const unsigned pk = (unsigned)(v.x & 255) | ((unsigned)(v.y & 255) << 8) |
                            ((unsigned)(v.z & 255) << 16) | ((unsigned)(v.w & 255) << 24);
        *reinterpret_cast<unsigned*>(qr + idx) = pk;
    }
    __shared__ int wsum[4];
    #pragma unroll
    for (int off = 32; off > 0; off >>= 1) lsum += __shfl_down(lsum, off);
    if ((t & 63) == 0) wsum[t >> 6] = lsum;
    __syncthreads();
    if (t == 0) sum_w[row] = wsum[0] + wsum[1] + wsum[2] + wsum[3];
}

// ---------------------------------------------------------------------------
// Kernel 3: int8 GEMM == round-8 EXACTLY (r6 skeleton, A-only LDS 4-slot,
// B direct global->VGPR double-buffered, XCD swizzle) with ONE change:
// every explicit s_waitcnt is vmcnt(0).
//
// Hypothesis under test: counted vmcnt(N) over a MIXED stream of
// global_load_lds (LDS-DMA) + regular global_load retires out-of-order on
// gfx950 -> vmcnt(6)/(4) could leave an A-stage pending while retiring newer
// B-loads -> stale LDS (r7/r8 failures). vmcnt(0) is hypothesis-independent.
// Cost is low: the drain sits ~1 full tile after A-stage issue and ~500cyc
// after B issue, so nearly all ops have already retired (unlike m97's
// drain-at-issue).
// ---------------------------------------------------------------------------
#define BM 256
#define BN 256
#define BKB 64
#define NSLOT 4

__device__ __forceinline__ void gload_lds16(const void* g, void* l) {
    __builtin_amdgcn_global_load_lds(
        (const __attribute__((address_space(1))) unsigned int*)g,
        (__attribute__((address_space(3))) unsigned int*)l, 16, 0, 0);
}

#define MFMA_I8 __builtin_amdgcn_mfma_i32_32x32x32_i8

__global__ __launch_bounds__(512, 2)
void gemm_i8_kernel(const int8_t* __restrict__ xq,
                    const int8_t* __restrict__ wq,
                    const int* __restrict__ sum_x,
                    const int* __restrict__ sum_w,
                    const float* __restrict__ bias,
                    float* __restrict__ out,
                    const float* __restrict__ p_sa,
                    const int* __restrict__ p_zpa,
                    const float* __restrict__ p_sw,
                    const int* __restrict__ p_wzp,
                    int M, int N, int K) {
    __shared__ v4i ldsA[NSLOT][1024];   // 4 slots * 16KB = 64 KiB (A only)

    const int tid = threadIdx.x;
    const int lane = tid & 63;
    const int wid = tid >> 6;
    const int wr = wid >> 2;            // 0..1: rows wr*128..+127
    const int wc = wid & 3;             // 0..3: cols wc*64..+63

    // XCD-aware bijective swizzle (nwg % 8 == 0 here: 32*16 = 512)
    const int nwgy = M / BM;
    const int nwg = nwgy * (N / BN);
    const int bid = blockIdx.x;
    const int v = (bid & 7) * (nwg >> 3) + (bid >> 3);
    const int m0 = (v % nwgy) * BM;     // y-fastest: each XCD sees 2 n-panels
    const int n0 = (v / nwgy) * BN;

    // ---- A staging: thread tid fills LDS chunk p = i*512 + tid.
    // row = i*128 + (tid>>2), stored chunk' = tid&3; source logical chunk =
    // chunk' ^ f(row), f(row) = ((row>>1)^(row>>3))&3.
    const int srow = tid >> 2;                          // 0..127
    const int schunk = (tid & 3) ^ (((srow >> 1) ^ (srow >> 3)) & 3);
    const int8_t* aS = xq + (size_t)(m0 + srow) * K + schunk * 16;
    const size_t half = (size_t)128 * K;                // +128 rows
    const int dbase = wid * 64;                         // wave-uniform LDS base

    // ---- A fragment reads (swizzled as stored)
    const int sel = ((lane >> 1) ^ (lane >> 3)) & 3;
    const int hi = lane >> 5;
    const int abase = (wr * 128 + (lane & 31)) * 4;     // chunk index base
    const int c00 = hi ^ sel;          // ks0 stored chunk
    const int c01 = (2 + hi) ^ sel;    // ks1 stored chunk

    // ---- B direct-from-global fragment pointer: lane l covers
    // row n0 + wc*64 + cf*32 + (l&31), kbyte t*64 + ks*32 + (l>>5)*16.
    const int8_t* bP = wq + (size_t)(n0 + wc * 64 + (lane & 31)) * K + ((lane >> 5) << 4);
    const size_t bcf = (size_t)32 * K;

    v16i acc[4][2] = {};
    v4i bfA[4], bfB[4];                 // named B double-buffer (rule 20)

    const int NT = K / BKB;             // 64 (even)

    // ---- prologue: stage A tiles 0,1; load B tile 0 into bfA; full drain
    gload_lds16(aS,             &ldsA[0][dbase]);
    gload_lds16(aS + half,      &ldsA[0][dbase + 512]);
    gload_lds16(aS + 64,        &ldsA[1][dbase]);
    gload_lds16(aS + half + 64, &ldsA[1][dbase + 512]);
    bfA[0] = *reinterpret_cast<const v4i*>(bP);
    bfA[1] = *reinterpret_cast<const v4i*>(bP + 32);
    bfA[2] = *reinterpret_cast<const v4i*>(bP + bcf);
    bfA[3] = *reinterpret_cast<const v4i*>(bP + bcf + 32);
    asm volatile("s_waitcnt vmcnt(0)" ::: "memory");
    __builtin_amdgcn_sched_barrier(0);
    __builtin_amdgcn_s_barrier();

    // One K-tile, r6 skeleton. BCUR = B regs for tile t; BNXT loaded with
    // B(t+1) in phase 1 (where B-staging sat in r6).
#define TILE(BCUR, BNXT, T_) do {                                             \
        const int t_ = (T_);                                                  \
        const v4i* LA = ldsA[t_ & 3];                                         \
        /* ============ phase 0: A rf0,rf1 reads; stage A(t+2) ============ */\
        const v4i a00 = LA[abase + c00];                                      \
        const v4i a01 = LA[abase + c01];                                      \
        const v4i a10 = LA[abase + 128 + c00];                                \
        const v4i a11 = LA[abase + 128 + c01];                                \
        if (t_ + 2 < NT) {                                                    \
            const int ns = (t_ + 2) & 3;                                      \
            const int8_t* p = aS + (size_t)(t_ + 2) * BKB;                    \
            gload_lds16(p,        &ldsA[ns][dbase]);                          \
            gload_lds16(p + half, &ldsA[ns][dbase + 512]);                    \
        }                                                                     \
        __builtin_amdgcn_s_barrier();                                         \
        __builtin_amdgcn_s_setprio(1);                                        \
        acc[0][0] = MFMA_I8(a00, BCUR[0], acc[0][0], 0, 0, 0);                \
        acc[0][1] = MFMA_I8(a00, BCUR[2], acc[0][1], 0, 0, 0);                \
        acc[1][0] = MFMA_I8(a10, BCUR[0], acc[1][0], 0, 0, 0);                \
        acc[1][1] = MFMA_I8(a10, BCUR[2], acc[1][1], 0, 0, 0);                \
        acc[0][0] = MFMA_I8(a01, BCUR[1], acc[0][0], 0, 0, 0);                \
        acc[0][1] = MFMA_I8(a01, BCUR[3], acc[0][1], 0, 0, 0);                \
        acc[1][0] = MFMA_I8(a11, BCUR[1], acc[1][0], 0, 0, 0);                \
        acc[1][1] = MFMA_I8(a11, BCUR[3], acc[1][1], 0, 0, 0);                \
        __builtin_amdgcn_s_setprio(0);                                        \
        __builtin_amdgcn_s_barrier();                                         \
        /* ============ phase 1: A rf2,rf3 reads; load B(t+1) ============= */\
        const v4i a20 = LA[abase + 256 + c00];                                \
        const v4i a21 = LA[abase + 256 + c01];                                \
        const v4i a30 = LA[abase + 384 + c00];                                \
        const v4i a31 = LA[abase + 384 + c01];                                \
        if (t_ + 1 < NT) {                                                    \
            const int8_t* q = bP + (size_t)(t_ + 1) * BKB;                    \
            BNXT[0] = *reinterpret_cast<const v4i*>(q);                       \
            BNXT[1] = *reinterpret_cast<const v4i*>(q + 32);                  \
            BNXT[2] = *reinterpret_cast<const v4i*>(q + bcf);                 \
            BNXT[3] = *reinterpret_cast<const v4i*>(q + bcf + 32);            \
        }                                                                     \
        __builtin_amdgcn_s_barrier();                                         \
        __builtin_amdgcn_s_setprio(1);                                        \
        acc[2][0] = MFMA_I8(a20, BCUR[0], acc[2][0], 0, 0, 0);                \
        acc[2][1] = MFMA_I8(a20, BCUR[2], acc[2][1], 0, 0, 0);                \
        acc[3][0] = MFMA_I8(a30, BCUR[0], acc[3][0], 0, 0, 0);                \
        acc[3][1] = MFMA_I8(a30, BCUR[2], acc[3][1], 0, 0, 0);                \
        acc[2][0] = MFMA_I8(a21, BCUR[1], acc[2][0], 0, 0, 0);                \
        acc[2][1] = MFMA_I8(a21, BCUR[3], acc[2][1], 0, 0, 0);                \
        acc[3][0] = MFMA_I8(a31, BCUR[1], acc[3][0], 0, 0, 0);                \
        acc[3][1] = MFMA_I8(a31, BCUR[3], acc[3][1], 0, 0, 0);                \
        __builtin_amdgcn_s_setprio(0);                                        \
        /* full drain: hypothesis-independent of mixed-op vmcnt ordering */   \
        asm volatile("s_waitcnt vmcnt(0)" ::: "memory");                      \
        __builtin_amdgcn_sched_barrier(0);                                    \
        __builtin_amdgcn_s_barrier();                                         \
    } while (0)

    for (int tt = 0; tt < NT; tt += 2) {
        TILE(bfA, bfB, tt);
        TILE(bfB, bfA, tt + 1);
    }
#undef TILE

    // ---- epilogue: y = (acc - wzp*sum_x[m] - zp*sum_w[n] + K*zp*wzp)*(sa*sw) + bias[n]
    const float stot = p_sa[0] * p_sw[0];
    const int zpa = p_zpa[0];
    const int wzp = p_wzp[0];
    const int kzz = K * zpa * wzp;
    const int coll = lane & 31;
    const int rhi = (lane >> 5) * 4;

    #pragma unroll
    for (int cf = 0; cf < 2; ++cf) {
        const int cg = n0 + wc * 64 + cf * 32 + coll;
        const int sw = sum_w[cg];
        const float bb = bias[cg];
        #pragma unroll
        for (int rf = 0; rf < 4; ++rf) {
            const int rbase = m0 + wr * 128 + rf * 32 + rhi;
            #pragma unroll
            for (int r = 0; r < 16; ++r) {
                const int rowg = rbase + (r & 3) + 8 * (r >> 2);
                const int iv = acc[rf][cf][r] - wzp * sum_x[rowg] - zpa * sw + kzz;
                out[(size_t)rowg * N + cg] = (float)iv * stot + bb;
            }
        }
    }
}

// ---------------------------------------------------------------------------
extern "C" void kernel_launch(void* const* d_in, const int* in_sizes, int n_in,
                              void* d_out, int out_size, void* d_ws, size_t ws_size,
                              hipStream_t stream) {
    const float* x     = (const float*)d_in[0];
    const int*   w     = (const int*)d_in[1];
    const float* bias  = (const float*)d_in[2];
    const float* p_sa  = (const float*)d_in[3];
    const int*   p_zpa = (const int*)d_in[4];
    const float* p_sw  = (const float*)d_in[5];
    const int*   p_wzp = (const int*)d_in[6];

    const int N = in_sizes[2];             // OUT
    const int K = in_sizes[1] / N;         // IN
    const int M = in_sizes[0] / K;         // B*S

    int8_t* xq = (int8_t*)d_ws;
    int8_t* wq = xq + (size_t)M * K;
    int* sum_x = (int*)(wq + (size_t)N * K);
    int* sum_w = sum_x + M;

    quant_x_kernel<<<M, 256, 0, stream>>>(x, xq, sum_x, p_sa, p_zpa, K);
    quant_w_kernel<<<N, 256, 0, stream>>>(w, wq, sum_w, K);

    const int nwg = (M / BM) * (N / BN);   // 512
    gemm_i8_kernel<<<nwg, 512, 0, stream>>>(xq, wq, sum_x, sum_w, bias,
                                            (float*)d_out, p_sa, p_zpa, p_sw, p_wzp,
                                            M, N, K);
}

// Round 10
// 238.362 us; speedup vs baseline: 1.3691x; 1.3691x over previous
//
#include <hip/hip_runtime.h>
#include <stdint.h>

typedef int v4i  __attribute__((ext_vector_type(4)));
typedef int v16i __attribute__((ext_vector_type(16)));

// ---------------------------------------------------------------------------
// Kernel 1: quantize activations fp32 -> int8, plus per-row sums.
// ---------------------------------------------------------------------------
__global__ void quant_x_kernel(const float* __restrict__ x,
                               int8_t* __restrict__ xq,
                               int* __restrict__ sum_x,
                               const float* __restrict__ p_scale,
                               const int* __restrict__ p_zp,
                               int K) {
    const int row = blockIdx.x;
    const int t = threadIdx.x;
    const float s = p_scale[0];
    const float zpf = (float)p_zp[0];
    const float* xr = x + (size_t)row * K;
    int8_t* qr = xq + (size_t)row * K;
    int lsum = 0;
    const int nchunk = K >> 10;
    for (int i = 0; i < nchunk; ++i) {
        const int idx = (i << 10) + (t << 2);
        const float4 v = *reinterpret_cast<const float4*>(xr + idx);
        const float f0 = fminf(fmaxf(rintf(v.x / s) + zpf, -128.f), 127.f);
        const float f1 = fminf(fmaxf(rintf(v.y / s) + zpf, -128.f), 127.f);
        const float f2 = fminf(fmaxf(rintf(v.z / s) + zpf, -128.f), 127.f);
        const float f3 = fminf(fmaxf(rintf(v.w / s) + zpf, -128.f), 127.f);
        const int i0 = (int)f0, i1 = (int)f1, i2 = (int)f2, i3 = (int)f3;
        lsum += i0 + i1 + i2 + i3;
        const unsigned pk = (unsigned)(i0 & 255) | ((unsigned)(i1 & 255) << 8) |
                            ((unsigned)(i2 & 255) << 16) | ((unsigned)(i3 & 255) << 24);
        *reinterpret_cast<unsigned*>(qr + idx) = pk;
    }
    __shared__ int wsum[4];
    #pragma unroll
    for (int off = 32; off > 0; off >>= 1) lsum += __shfl_down(lsum, off);
    if ((t & 63) == 0) wsum[t >> 6] = lsum;
    __syncthreads();
    if (t == 0) sum_x[row] = wsum[0] + wsum[1] + wsum[2] + wsum[3];
}

// ---------------------------------------------------------------------------
// Kernel 2: pack weight int32 (int8-valued) -> int8, plus per-row sums.
// ---------------------------------------------------------------------------
__global__ void quant_w_kernel(const int* __restrict__ w,
                               int8_t* __restrict__ wq,
                               int* __restrict__ sum_w,
                               int K) {
    const int row = blockIdx.x;
    const int t = threadIdx.x;
    const int* wr_ = w + (size_t)row * K;
    int8_t* qr = wq + (size_t)row * K;
    int lsum = 0;
    const int nchunk = K >> 10;
    for (int i = 0; i < nchunk; ++i) {
        const int idx = (i << 10) + (t << 2);
        const int4 v = *reinterpret_cast<const int4*>(wr_ + idx);
        lsum += v.x + v.y + v.z + v.w;
        const unsigned pk = (unsigned)(v.x & 255) | ((unsigned)(v.y & 255) << 8) |
                            ((unsigned)(v.z & 255) << 16) | ((unsigned)(v.w & 255) << 24);
        *reinterpret_cast<unsigned*>(qr + idx) = pk;
    }
    __shared__ int wsum[4];
    #pragma unroll
    for (int off = 32; off > 0; off >>= 1) lsum += __shfl_down(lsum, off);
    if ((t & 63) == 0) wsum[t >> 6] = lsum;
    __syncthreads();
    if (t == 0) sum_w[row] = wsum[0] + wsum[1] + wsum[2] + wsum[3];
}

// ---------------------------------------------------------------------------
// Kernel 3: int8 GEMM, 256x256 tile, 4 WAVES (2x2), wave-tile 128x128.
// Pure-DMA staging (A and B both via global_load_lds -- the r3-r6 verified
// counted-vmcnt stream), 4 slots, prefetch distance 2, ONE barrier + ONE
// vmcnt(8) per K-tile.
//
// Why 4 waves: i8's matrix pipe is 2x bf16 per byte, so the 8-wave template
// is LDS-READ-bound (reads 96KB/tile = 1130cyc > MFMA 1171... co-critical,
// and serial-sum in lockstep). 128x128 wave-tile halves fragment duplication
// (A dup 2x, B dup 2x): reads 64KB/tile = 753cyc < MFMA -> MFMA-dominant.
// 16 ds_reads feed 32 MFMAs per wave per tile. acc = 256 AGPR (1 wave/SIMD,
// ~350 regs total < 450 spill line) -- lockstep anyway, occupancy moot.
//
// Slot safety with 1 barrier/tile: data for tile t staged at t-2; each
// wave's own vmcnt(8) at end of t-1 retires its t-staging (pure in-order DMA
// stream); the barrier publishes cross-wave. WAR: slot (t+2)&3 overwritten
// at tile t; last read at t-2, >= 2 barriers earlier. Waves can't be >1 tile
// apart (barrier each tile).
//
// Swizzle (r6, verified): stored chunk' = chunk ^ f(row),
// f(row)=((row>>1)^(row>>3))&3; linear DMA dest + inverse-swizzled source.
// ---------------------------------------------------------------------------
#define BM 256
#define BN 256
#define BKB 64
#define NSLOT 4

__device__ __forceinline__ void gload_lds16(const void* g, void* l) {
    __builtin_amdgcn_global_load_lds(
        (const __attribute__((address_space(1))) unsigned int*)g,
        (__attribute__((address_space(3))) unsigned int*)l, 16, 0, 0);
}

#define MFMA_I8 __builtin_amdgcn_mfma_i32_32x32x32_i8

__global__ __launch_bounds__(256, 1)
void gemm_i8_kernel(const int8_t* __restrict__ xq,
                    const int8_t* __restrict__ wq,
                    const int* __restrict__ sum_x,
                    const int* __restrict__ sum_w,
                    const float* __restrict__ bias,
                    float* __restrict__ out,
                    const float* __restrict__ p_sa,
                    const int* __restrict__ p_zpa,
                    const float* __restrict__ p_sw,
                    const int* __restrict__ p_wzp,
                    int M, int N, int K) {
    __shared__ v4i ldsA[NSLOT][1024];   // 4 slots * 16KB = 64 KiB
    __shared__ v4i ldsB[NSLOT][1024];   // 128 KiB total

    const int tid = threadIdx.x;        // 256 threads = 4 waves
    const int lane = tid & 63;
    const int wid = tid >> 6;
    const int wr = wid >> 1;            // 0..1: rows wr*128..+127
    const int wc = wid & 1;             // 0..1: cols wc*128..+127

    // XCD-aware bijective swizzle (nwg = 512, %8 == 0)
    const int nwgy = M / BM;
    const int nwg = nwgy * (N / BN);
    const int bid = blockIdx.x;
    const int v = (bid & 7) * (nwg >> 3) + (bid >> 3);
    const int m0 = (v % nwgy) * BM;
    const int n0 = (v / nwgy) * BN;

    // ---- staging: thread tid handles chunks {tid + k*256, k=0..3} per
    // operand per tile. chunk p: row = p>>2, stored chunk' = p&3.
    // srow = tid>>2 (0..63); row = srow + k*64 (f(row) independent of k).
    const int srow = tid >> 2;
    const int schunk = (tid & 3) ^ (((srow >> 1) ^ (srow >> 3)) & 3);
    const int8_t* aS = xq + (size_t)(m0 + srow) * K + schunk * 16;
    const int8_t* bS = wq + (size_t)(n0 + srow) * K + schunk * 16;
    const size_t qtr = (size_t)64 * K;                  // +64 rows
    const int dbase = wid * 64;                         // wave-uniform

    // ---- fragment reads: row = (wr|wc)*128 + f_idx*32 + (lane&31),
    // logical chunk c = ks*2 + (lane>>5); stored at c ^ f(row).
    const int sel = ((lane >> 1) ^ (lane >> 3)) & 3;
    const int hi = lane >> 5;
    const int c0 = hi ^ sel;            // ks0 stored chunk
    const int c1 = (2 + hi) ^ sel;      // ks1 stored chunk
    int arow[4], brow[4];
    #pragma unroll
    for (int i = 0; i < 4; ++i) {
        arow[i] = (wr * 128 + i * 32 + (lane & 31)) * 4;
        brow[i] = (wc * 128 + i * 32 + (lane & 31)) * 4;
    }

    v16i acc[4][4] = {};
    const int NT = K / BKB;             // 64

#define STAGE(SLOT, T_) do {                                                  \
        const int8_t* pa_ = aS + (size_t)(T_) * BKB;                          \
        const int8_t* pb_ = bS + (size_t)(T_) * BKB;                          \
        _Pragma("unroll")                                                     \
        for (int k_ = 0; k_ < 4; ++k_) {                                      \
            gload_lds16(pa_ + k_ * qtr, &ldsA[SLOT][k_ * 256 + dbase]);       \
            gload_lds16(pb_ + k_ * qtr, &ldsB[SLOT][k_ * 256 + dbase]);       \
        }                                                                     \
    } while (0)

    // ---- prologue: stage tiles 0 and 1 (8 DMA each)
    STAGE(0, 0);
    STAGE(1, 1);
    asm volatile("s_waitcnt vmcnt(8)" ::: "memory");   // tile 0 landed
    __builtin_amdgcn_sched_barrier(0);
    __builtin_amdgcn_s_barrier();

    for (int t = 0; t < NT; ++t) {
        const v4i* LA = ldsA[t & 3];
        const v4i* LB = ldsB[t & 3];
        v4i a[4][2], b[4][2];
        #pragma unroll
        for (int i = 0; i < 4; ++i) {
            a[i][0] = LA[arow[i] + c0];
            a[i][1] = LA[arow[i] + c1];
        }
        #pragma unroll
        for (int i = 0; i < 4; ++i) {
            b[i][0] = LB[brow[i] + c0];
            b[i][1] = LB[brow[i] + c1];
        }
        if (t + 2 < NT) STAGE((t + 2) & 3, t + 2);
        __builtin_amdgcn_s_setprio(1);
        #pragma unroll
        for (int ks = 0; ks < 2; ++ks)
            #pragma unroll
            for (int rf = 0; rf < 4; ++rf)
                #pragma unroll
                for (int cf = 0; cf < 4; ++cf)
                    acc[rf][cf] = MFMA_I8(a[rf][ks], b[cf][ks], acc[rf][cf], 0, 0, 0);
        __builtin_amdgcn_s_setprio(0);
        // counted wait on the PURE DMA stream: this tile issued 8 (t+2);
        // waiting to 8 retires tile t+1's stages (in-order, r3-r6 verified).
        if (t + 2 < NT) {
            asm volatile("s_waitcnt vmcnt(8)" ::: "memory");
        } else if (t + 1 < NT) {
            asm volatile("s_waitcnt vmcnt(0)" ::: "memory");
        }
        __builtin_amdgcn_sched_barrier(0);
        __builtin_amdgcn_s_barrier();
    }
#undef STAGE

    // ---- epilogue: y = (acc - wzp*sum_x[m] - zp*sum_w[n] + K*zp*wzp)*(sa*sw) + bias[n]
    const float stot = p_sa[0] * p_sw[0];
    const int zpa = p_zpa[0];
    const int wzp = p_wzp[0];
    const int kzz = K * zpa * wzp;
    const int coll = lane & 31;
    const int rhi = (lane >> 5) * 4;

    #pragma unroll
    for (int cf = 0; cf < 4; ++cf) {
        const int cg = n0 + wc * 128 + cf * 32 + coll;
        const int sw = sum_w[cg];
        const float bb = bias[cg];
        #pragma unroll
        for (int rf = 0; rf < 4; ++rf) {
            const int rbase = m0 + wr * 128 + rf * 32 + rhi;
            #pragma unroll
            for (int r = 0; r < 16; ++r) {
                const int rowg = rbase + (r & 3) + 8 * (r >> 2);
                const int iv = acc[rf][cf][r] - wzp * sum_x[rowg] - zpa * sw + kzz;
                out[(size_t)rowg * N + cg] = (float)iv * stot + bb;
            }
        }
    }
}

// ---------------------------------------------------------------------------
extern "C" void kernel_launch(void* const* d_in, const int* in_sizes, int n_in,
                              void* d_out, int out_size, void* d_ws, size_t ws_size,
                              hipStream_t stream) {
    const float* x     = (const float*)d_in[0];
    const int*   w     = (const int*)d_in[1];
    const float* bias  = (const float*)d_in[2];
    const float* p_sa  = (const float*)d_in[3];
    const int*   p_zpa = (const int*)d_in[4];
    const float* p_sw  = (const float*)d_in[5];
    const int*   p_wzp = (const int*)d_in[6];

    const int N = in_sizes[2];             // OUT
    const int K = in_sizes[1] / N;         // IN
    const int M = in_sizes[0] / K;         // B*S

    int8_t* xq = (int8_t*)d_ws;
    int8_t* wq = xq + (size_t)M * K;
    int* sum_x = (int*)(wq + (size_t)N * K);
    int* sum_w = sum_x + M;

    quant_x_kernel<<<M, 256, 0, stream>>>(x, xq, sum_x, p_sa, p_zpa, K);
    quant_w_kernel<<<N, 256, 0, stream>>>(w, wq, sum_w, K);

    const int nwg = (M / BM) * (N / BN);   // 512
    gemm_i8_kernel<<<nwg, 256, 0, stream>>>(xq, wq, sum_x, sum_w, bias,
                                            (float*)d_out, p_sa, p_zpa, p_sw, p_wzp,
                                            M, N, K);
}